// Round 6
// baseline (235.883 us; speedup 1.0000x reference)
//
#include <hip/hip_runtime.h>
#include <math.h>

#define NPTS   8192
#define DDIM   128
#define NBLK2  32            // 8192 / 256 row-super-blocks
#define NTRI2  528           // NBLK2*(NBLK2+1)/2 super-tiles
#define NCLS   50

using short8 = __attribute__((ext_vector_type(8))) short;
using f32x4  = __attribute__((ext_vector_type(4))) float;

__device__ __forceinline__ unsigned short f2bf(float f) {
    unsigned int u = __float_as_uint(f);
    u += 0x7fffu + ((u >> 16) & 1u);
    return (unsigned short)(u >> 16);
}
__device__ __forceinline__ float bf2f(unsigned short s) {
    return __uint_as_float(((unsigned int)s) << 16);
}

// async 16B/lane global->LDS DMA (dest = wave-uniform base + lane*16)
__device__ __forceinline__ void gld_lds16(const unsigned short* g, unsigned short* l) {
    __builtin_amdgcn_global_load_lds(
        (const __attribute__((address_space(1))) unsigned int*)g,
        (__attribute__((address_space(3))) unsigned int*)l,
        16, 0, 0);
}

// --- kernel 1: convert X -> bf16 once; sq[i] = ||bf16(x_i)||^2 ---
__global__ __launch_bounds__(256) void prep_kernel(
    const float* __restrict__ X, unsigned short* __restrict__ Xbf,
    float* __restrict__ sq, float* __restrict__ posG)
{
    if (blockIdx.x == 0 && threadIdx.x == 0) posG[0] = 0.f;   // zero accumulator
    const int wave = threadIdx.x >> 6, lane = threadIdx.x & 63;
    const int row  = blockIdx.x * 4 + wave;
    float2 v = *(const float2*)(X + (size_t)row * DDIM + lane * 2);
    unsigned short a = f2bf(v.x), b = f2bf(v.y);
    float fa = bf2f(a), fb = bf2f(b);
    float s = fa * fa + fb * fb;
    *(ushort2*)(Xbf + (size_t)row * DDIM + lane * 2) = make_ushort2(a, b);
#pragma unroll
    for (int off = 32; off > 0; off >>= 1) s += __shfl_down(s, off);
    if (lane == 0) sq[row] = s;
}

// --- kernel 1b: per-class mean vectors -> posG = sum_c ||m_c||^2 ---
// 50 blocks (one per class) x 1024 threads (8 row-partitions x 128 cols).
__global__ __launch_bounds__(1024) void classsum_kernel(
    const unsigned short* __restrict__ Xbf, const int* __restrict__ lab,
    float* __restrict__ posG)
{
    __shared__ float sm[1024];
    __shared__ float sred[2];
    const int c    = blockIdx.x;
    const int part = threadIdx.x >> 7;   // 0..7
    const int col  = threadIdx.x & 127;
    float acc = 0.f;
    const int r0 = part * 1024, r1 = r0 + 1024;
    for (int r = r0; r < r1; ++r) {      // label check is wave-uniform
        if (lab[r] == c)
            acc += bf2f(Xbf[(size_t)r * DDIM + col]);
    }
    sm[threadIdx.x] = acc;
    __syncthreads();
    if (part == 0) {                     // threads 0..127: combine partitions
        float m = 0.f;
#pragma unroll
        for (int p = 0; p < 8; ++p) m += sm[p * 128 + col];
        float m2 = m * m;
#pragma unroll
        for (int off = 32; off > 0; off >>= 1) m2 += __shfl_down(m2, off);
        if ((threadIdx.x & 63) == 0) sred[threadIdx.x >> 6] = m2;
    }
    __syncthreads();
    if (threadIdx.x == 0) atomicAdd(posG, sred[0] + sred[1]);
}

// --- kernel 2: 256x256 super-tiles, 8 waves (2x4), single stage per block.
// Epilogue is now only the hinge-support test: per element 2 VALU
// (gm_j = max(gm_j, g - 0.5*sa); flag iff gm_j > 0.5*sb_j - 2  <=>  d < 4).
// Slow path (diag blocks / genuinely close pairs) does the exact label-masked
// hinge sum. Positive term is computed analytically (classsum + finalize).
// LDS panels (ushort idx): A=[0,32768), B=[32768,65536).
// Panel layout: tile[r][s] = X[row0+r][8*(s ^ (r&7))]  (XOR swizzle, s=16B slot)
__global__ __launch_bounds__(512, 2) void pair_kernel(
    const unsigned short* __restrict__ Xbf, const int* __restrict__ lab,
    const float* __restrict__ sq, float* __restrict__ slots /* [NTRI2] */)
{
    const int k = blockIdx.x;
    int bi = (int)((65.0f - sqrtf((float)(4225 - 8 * k))) * 0.5f);
    if (bi < 0) bi = 0;
    while (32 * (bi + 1) - ((bi + 1) * bi) / 2 <= k) ++bi;   // O(bi+1) <= k
    while (32 * bi - (bi * (bi - 1)) / 2 > k) --bi;          // O(bi)   >  k
    const int bj = bi + (k - (32 * bi - (bi * (bi - 1)) / 2));

    __shared__ unsigned short tile[65536];   // 128 KB: A=[0,32768), B=[32768,65536)
    __shared__ __attribute__((aligned(16))) float sSqA[256];
    __shared__ __attribute__((aligned(16))) float sSqB[256];
    __shared__ __attribute__((aligned(16))) int   sLabA[256];
    __shared__ __attribute__((aligned(16))) int   sLabB[256];
    __shared__ float rN[8];

    const int tid   = threadIdx.x;
    const int rowA0 = bi * 256;
    const int rowB0 = bj * 256;

    // ---- async staging of both 256x128 bf16 panels ----
    {
        const int rloc = tid >> 4;                        // 0..31: row within 32-row stripe
        const int cswz = ((tid & 15) ^ (rloc & 7)) * 8;   // pre-swizzled source column
        const unsigned short* gA = Xbf + (size_t)(rowA0 + rloc) * DDIM + cswz;
        const unsigned short* gB = Xbf + (size_t)(rowB0 + rloc) * DDIM + cswz;
        unsigned short* lA = &tile[(tid & ~63) * 8];          // wave-uniform base
        unsigned short* lB = &tile[32768 + (tid & ~63) * 8];
#pragma unroll
        for (int i = 0; i < 8; ++i)                       // rows i*32 + rloc
            gld_lds16(gA + (size_t)i * 32 * DDIM, lA + i * 4096);
#pragma unroll
        for (int i = 0; i < 8; ++i)
            gld_lds16(gB + (size_t)i * 32 * DDIM, lB + i * 4096);
    }

    if (tid < 256) { sSqA[tid] = sq[rowA0 + tid];        sLabA[tid] = lab[rowA0 + tid]; }
    else           { sSqB[tid - 256] = sq[rowB0 + tid - 256];
                     sLabB[tid - 256] = lab[rowB0 + tid - 256]; }
    __syncthreads();   // drains DMA (vmcnt) + LDS writes; the only staging barrier

    const int wave = tid >> 6, lane = tid & 63;
    const int quad = lane >> 4, rr = lane & 15;
    const int wr = wave >> 2, wc = wave & 3;    // 2 x 4 wave grid, 128x64 per wave
    const int r7 = rr & 7;

    const unsigned short* tA = &tile[(size_t)(wr * 128 + rr) * 128];
    const unsigned short* tB = &tile[32768 + (size_t)(wc * 64 + rr) * 128];

    f32x4 acc[8][4];
#pragma unroll
    for (int i = 0; i < 8; ++i)
#pragma unroll
        for (int j = 0; j < 4; ++j)
            acc[i][j] = (f32x4){0.f, 0.f, 0.f, 0.f};

#pragma unroll
    for (int kc = 0; kc < 4; ++kc) {            // K = 128 in 4 chunks of 32
        const int s = (((kc * 4 + quad) ^ r7)) * 8;   // swizzled 16B slot
        short8 b4[4];
#pragma unroll
        for (int u = 0; u < 4; ++u)
            b4[u] = *(const short8*)(tB + u * 16 * 128 + s);
        short8 a0[4];
#pragma unroll
        for (int u = 0; u < 4; ++u)
            a0[u] = *(const short8*)(tA + u * 16 * 128 + s);
#pragma unroll
        for (int i = 0; i < 4; ++i)
#pragma unroll
            for (int j = 0; j < 4; ++j)
                acc[i][j] = __builtin_amdgcn_mfma_f32_16x16x32_bf16(a0[i], b4[j], acc[i][j], 0, 0, 0);
        short8 a1[4];
#pragma unroll
        for (int u = 0; u < 4; ++u)
            a1[u] = *(const short8*)(tA + (4 + u) * 16 * 128 + s);
#pragma unroll
        for (int i = 0; i < 4; ++i)
#pragma unroll
            for (int j = 0; j < 4; ++j)
                acc[4 + i][j] = __builtin_amdgcn_mfma_f32_16x16x32_bf16(a1[i], b4[j], acc[4 + i][j], 0, 0, 0);
    }

    // ---- fast epilogue: hinge-support test only ----
    // C/D layout: col = lane&15, row = quad*4 + reg (verified)
    float hb[4];
#pragma unroll
    for (int j = 0; j < 4; ++j)
        hb[j] = 0.5f * sSqB[wc * 64 + j * 16 + rr] - 2.0f;

    float gm[4] = {-1e30f, -1e30f, -1e30f, -1e30f};
#pragma unroll
    for (int i = 0; i < 8; ++i) {
        const f32x4 sa4 = *(const f32x4*)&sSqA[wr * 128 + i * 16 + quad * 4];
#pragma unroll
        for (int rg = 0; rg < 4; ++rg) {
            const float ha = -0.5f * sa4[rg];
#pragma unroll
            for (int j = 0; j < 4; ++j)
                gm[j] = fmaxf(gm[j], acc[i][j][rg] + ha);
        }
    }

    float negS = 0.f;
    const bool wf = (gm[0] > hb[0]) | (gm[1] > hb[1]) | (gm[2] > hb[2]) | (gm[3] > hb[3]);
    if (__any(wf)) {   // rare: some pair has d < 4 (incl. self-pairs on diag blocks)
        float sb[4]; int lbv[4];
#pragma unroll
        for (int j = 0; j < 4; ++j) {
            int cl = wc * 64 + j * 16 + rr;
            sb[j]  = sSqB[cl];
            lbv[j] = sLabB[cl];
        }
#pragma unroll
        for (int i = 0; i < 8; ++i) {
            const f32x4 sa4 = *(const f32x4*)&sSqA[wr * 128 + i * 16 + quad * 4];
            const int4  la4 = *(const int4*)&sLabA[wr * 128 + i * 16 + quad * 4];
#pragma unroll
            for (int rg = 0; rg < 4; ++rg) {
                float sa = sa4[rg];
                int   la = ((const int*)&la4)[rg];
#pragma unroll
                for (int j = 0; j < 4; ++j) {
                    float d = fmaxf(sa + sb[j] - 2.0f * acc[i][j][rg], 0.0f);
                    float h = fmaxf(2.0f - sqrtf(d + 1e-9f), 0.f);
                    negS += (la == lbv[j]) ? 0.f : h * h;
                }
            }
        }
    }

    negS *= (bi == bj) ? 1.0f : 2.0f;

#pragma unroll
    for (int off = 32; off > 0; off >>= 1)
        negS += __shfl_down(negS, off);
    if (lane == 0) rN[wave] = negS;
    __syncthreads();
    if (tid == 0) {
        float tn = 0.f;
#pragma unroll
        for (int w = 0; w < 8; ++w) tn += rN[w];
        slots[k] = tn;
    }
}

// --- kernel 3: histogram + pos (analytic) + neg slot reduce + combine ---
__global__ __launch_bounds__(1024) void finalize_kernel(
    const float* __restrict__ slots, const int* __restrict__ lab,
    const float* __restrict__ sq, const float* __restrict__ posG,
    float* __restrict__ out)
{
    __shared__ int   hist[64];
    __shared__ float sP[16], sN[16];
    const int tid = threadIdx.x;
    if (tid < 64) hist[tid] = 0;
    __syncthreads();
    for (int i = tid; i < NPTS; i += 1024) atomicAdd(&hist[lab[i]], 1);
    __syncthreads();

    float p = 0.f, n = 0.f;
    for (int i = tid; i < NPTS; i += 1024) p += sq[i] * (float)hist[lab[i]];  // sum_c n_c S_c
    for (int i = tid; i < NTRI2; i += 1024) n += slots[i];
#pragma unroll
    for (int off = 32; off > 0; off >>= 1) {
        p += __shfl_down(p, off);
        n += __shfl_down(n, off);
    }
    const int wave = tid >> 6, lane = tid & 63;
    if (lane == 0) { sP[wave] = p; sN[wave] = n; }
    __syncthreads();
    if (tid == 0) {
        long long np = 0;
        for (int c = 0; c < 64; ++c) np += (long long)hist[c] * hist[c];
        float tp = 0.f, tn = 0.f;
#pragma unroll
        for (int w = 0; w < 16; ++w) { tp += sP[w]; tn += sN[w]; }
        double dnp = (double)np;
        double dnn = (double)NPTS * (double)NPTS - dnp;
        // dist_pos = 2*sum_c n_c S_c - 2*sum_c ||m_c||^2 ; pos = 0.5*dist_pos/np
        double pt = (dnp > 0.0) ? ((double)tp - (double)posG[0]) / dnp : 0.0;
        double nt = (dnn > 0.0) ? 0.5 * (double)tn / dnn : 0.0;
        out[0] = (float)(pt + nt);
    }
}

extern "C" void kernel_launch(void* const* d_in, const int* in_sizes, int n_in,
                              void* d_out, int out_size, void* d_ws, size_t ws_size,
                              hipStream_t stream) {
    const float* X   = (const float*)d_in[0];
    const int*   lab = (const int*)d_in[1];
    float*       out = (float*)d_out;

    char* ws = (char*)d_ws;
    unsigned short* Xbf   = (unsigned short*)(ws);                      // 2 MB
    float*          sq    = (float*)(ws + 2 * 1024 * 1024);             // 32 KB
    float*          slots = (float*)(ws + 2 * 1024 * 1024 + 32 * 1024); // 2.1 KB
    float*          posG  = (float*)(ws + 2 * 1024 * 1024 + 64 * 1024); // 4 B

    prep_kernel<<<NPTS / 4, 256, 0, stream>>>(X, Xbf, sq, posG);
    classsum_kernel<<<NCLS, 1024, 0, stream>>>(Xbf, lab, posG);
    pair_kernel<<<NTRI2, 512, 0, stream>>>(Xbf, lab, sq, slots);
    finalize_kernel<<<1, 1024, 0, stream>>>(slots, lab, sq, posG, out);
}

// Round 7
// 108.779 us; speedup vs baseline: 2.1685x; 2.1685x over previous
//
#include <hip/hip_runtime.h>
#include <math.h>

#define NPTS   8192
#define DDIM   128
#define NBLK2  32            // 8192 / 256 row-super-blocks
#define NTRI2  528           // NBLK2*(NBLK2+1)/2 super-tiles
#define NCLS   50
#define CSBLK  256           // classsum blocks (32 rows each)

using short8 = __attribute__((ext_vector_type(8))) short;
using f32x4  = __attribute__((ext_vector_type(4))) float;

__device__ __forceinline__ unsigned short f2bf(float f) {
    unsigned int u = __float_as_uint(f);
    u += 0x7fffu + ((u >> 16) & 1u);
    return (unsigned short)(u >> 16);
}
__device__ __forceinline__ float bf2f(unsigned short s) {
    return __uint_as_float(((unsigned int)s) << 16);
}

// async 16B/lane global->LDS DMA (dest = wave-uniform base + lane*16)
__device__ __forceinline__ void gld_lds16(const unsigned short* g, unsigned short* l) {
    __builtin_amdgcn_global_load_lds(
        (const __attribute__((address_space(1))) unsigned int*)g,
        (__attribute__((address_space(3))) unsigned int*)l,
        16, 0, 0);
}

// --- kernel 1: convert X -> bf16 once; sq[i] = ||bf16(x_i)||^2 ---
__global__ __launch_bounds__(256) void prep_kernel(
    const float* __restrict__ X, unsigned short* __restrict__ Xbf,
    float* __restrict__ sq, float* __restrict__ posG)
{
    if (blockIdx.x == 0 && threadIdx.x == 0) posG[0] = 0.f;   // zero accumulator
    const int wave = threadIdx.x >> 6, lane = threadIdx.x & 63;
    const int row  = blockIdx.x * 4 + wave;
    float2 v = *(const float2*)(X + (size_t)row * DDIM + lane * 2);
    unsigned short a = f2bf(v.x), b = f2bf(v.y);
    float fa = bf2f(a), fb = bf2f(b);
    float s = fa * fa + fb * fb;
    *(ushort2*)(Xbf + (size_t)row * DDIM + lane * 2) = make_ushort2(a, b);
#pragma unroll
    for (int off = 32; off > 0; off >>= 1) s += __shfl_down(s, off);
    if (lane == 0) sq[row] = s;
}

// --- kernel 1b stage A: per-block partial class-sum vectors ---
// 256 blocks x 32 rows. 16 rows in parallel, each row by 16 threads x short8
// (vectorized 16B loads). LDS atomicAdd handles same-class row collisions.
__global__ __launch_bounds__(256) void classsum_kernel(
    const unsigned short* __restrict__ Xbf, const int* __restrict__ lab,
    float* __restrict__ partial /* [CSBLK][NCLS*DDIM] */)
{
    __shared__ float lacc[NCLS * DDIM];   // 25.6 KB
    const int tid = threadIdx.x;
    for (int i = tid; i < NCLS * DDIM; i += 256) lacc[i] = 0.f;
    __syncthreads();

    const int rsub = tid >> 4;            // 0..15: row within 16-row wavefront
    const int cseg = (tid & 15) * 8;      // col base (8 bf16 per thread)
    const int r0   = blockIdx.x * 32;
#pragma unroll
    for (int it = 0; it < 2; ++it) {
        const int r = r0 + it * 16 + rsub;
        const int c = lab[r];
        short8 v = *(const short8*)(Xbf + (size_t)r * DDIM + cseg);
        float* dst = &lacc[c * DDIM + cseg];
#pragma unroll
        for (int e = 0; e < 8; ++e)
            atomicAdd(&dst[e], bf2f((unsigned short)v[e]));
    }
    __syncthreads();
    float* out = partial + (size_t)blockIdx.x * (NCLS * DDIM);
    for (int i = tid; i < NCLS * DDIM; i += 256) out[i] = lacc[i];
}

// --- kernel 1b stage B: reduce partials, posG = sum_c ||v_c||^2 ---
// 25 blocks x 256 threads = 6400 threads, one per (class, col).
__global__ __launch_bounds__(256) void classred_kernel(
    const float* __restrict__ partial, float* __restrict__ posG)
{
    const int idx = blockIdx.x * 256 + threadIdx.x;   // 0..6399
    float m = 0.f;
    for (int b = 0; b < CSBLK; ++b)
        m += partial[(size_t)b * (NCLS * DDIM) + idx];
    float m2 = m * m;
#pragma unroll
    for (int off = 32; off > 0; off >>= 1) m2 += __shfl_down(m2, off);
    __shared__ float sred[4];
    if ((threadIdx.x & 63) == 0) sred[threadIdx.x >> 6] = m2;
    __syncthreads();
    if (threadIdx.x == 0) atomicAdd(posG, sred[0] + sred[1] + sred[2] + sred[3]);
}

// --- kernel 2: 256x256 super-tiles, 8 waves (2x4), single stage per block.
// Epilogue: hinge-support test only (2 VALU/element); slow path (diag blocks /
// genuinely close pairs) does the exact label-masked hinge sum. Positive term
// is analytic (classsum/classred + finalize).
// LDS panels (ushort idx): A=[0,32768), B=[32768,65536).
// Panel layout: tile[r][s] = X[row0+r][8*(s ^ (r&7))]  (XOR swizzle, s=16B slot)
__global__ __launch_bounds__(512, 2) void pair_kernel(
    const unsigned short* __restrict__ Xbf, const int* __restrict__ lab,
    const float* __restrict__ sq, float* __restrict__ slots /* [NTRI2] */)
{
    const int k = blockIdx.x;
    int bi = (int)((65.0f - sqrtf((float)(4225 - 8 * k))) * 0.5f);
    if (bi < 0) bi = 0;
    while (32 * (bi + 1) - ((bi + 1) * bi) / 2 <= k) ++bi;   // O(bi+1) <= k
    while (32 * bi - (bi * (bi - 1)) / 2 > k) --bi;          // O(bi)   >  k
    const int bj = bi + (k - (32 * bi - (bi * (bi - 1)) / 2));

    __shared__ unsigned short tile[65536];   // 128 KB: A=[0,32768), B=[32768,65536)
    __shared__ __attribute__((aligned(16))) float sSqA[256];
    __shared__ __attribute__((aligned(16))) float sSqB[256];
    __shared__ __attribute__((aligned(16))) int   sLabA[256];
    __shared__ __attribute__((aligned(16))) int   sLabB[256];
    __shared__ float rN[8];

    const int tid   = threadIdx.x;
    const int rowA0 = bi * 256;
    const int rowB0 = bj * 256;

    // ---- async staging of both 256x128 bf16 panels ----
    {
        const int rloc = tid >> 4;                        // 0..31: row within 32-row stripe
        const int cswz = ((tid & 15) ^ (rloc & 7)) * 8;   // pre-swizzled source column
        const unsigned short* gA = Xbf + (size_t)(rowA0 + rloc) * DDIM + cswz;
        const unsigned short* gB = Xbf + (size_t)(rowB0 + rloc) * DDIM + cswz;
        unsigned short* lA = &tile[(tid & ~63) * 8];          // wave-uniform base
        unsigned short* lB = &tile[32768 + (tid & ~63) * 8];
#pragma unroll
        for (int i = 0; i < 8; ++i)                       // rows i*32 + rloc
            gld_lds16(gA + (size_t)i * 32 * DDIM, lA + i * 4096);
#pragma unroll
        for (int i = 0; i < 8; ++i)
            gld_lds16(gB + (size_t)i * 32 * DDIM, lB + i * 4096);
    }

    if (tid < 256) { sSqA[tid] = sq[rowA0 + tid];        sLabA[tid] = lab[rowA0 + tid]; }
    else           { sSqB[tid - 256] = sq[rowB0 + tid - 256];
                     sLabB[tid - 256] = lab[rowB0 + tid - 256]; }
    __syncthreads();   // drains DMA (vmcnt) + LDS writes; the only staging barrier

    const int wave = tid >> 6, lane = tid & 63;
    const int quad = lane >> 4, rr = lane & 15;
    const int wr = wave >> 2, wc = wave & 3;    // 2 x 4 wave grid, 128x64 per wave
    const int r7 = rr & 7;

    const unsigned short* tA = &tile[(size_t)(wr * 128 + rr) * 128];
    const unsigned short* tB = &tile[32768 + (size_t)(wc * 64 + rr) * 128];

    f32x4 acc[8][4];
#pragma unroll
    for (int i = 0; i < 8; ++i)
#pragma unroll
        for (int j = 0; j < 4; ++j)
            acc[i][j] = (f32x4){0.f, 0.f, 0.f, 0.f};

#pragma unroll
    for (int kc = 0; kc < 4; ++kc) {            // K = 128 in 4 chunks of 32
        const int s = (((kc * 4 + quad) ^ r7)) * 8;   // swizzled 16B slot
        short8 b4[4];
#pragma unroll
        for (int u = 0; u < 4; ++u)
            b4[u] = *(const short8*)(tB + u * 16 * 128 + s);
        short8 a0[4];
#pragma unroll
        for (int u = 0; u < 4; ++u)
            a0[u] = *(const short8*)(tA + u * 16 * 128 + s);
#pragma unroll
        for (int i = 0; i < 4; ++i)
#pragma unroll
            for (int j = 0; j < 4; ++j)
                acc[i][j] = __builtin_amdgcn_mfma_f32_16x16x32_bf16(a0[i], b4[j], acc[i][j], 0, 0, 0);
        short8 a1[4];
#pragma unroll
        for (int u = 0; u < 4; ++u)
            a1[u] = *(const short8*)(tA + (4 + u) * 16 * 128 + s);
#pragma unroll
        for (int i = 0; i < 4; ++i)
#pragma unroll
            for (int j = 0; j < 4; ++j)
                acc[4 + i][j] = __builtin_amdgcn_mfma_f32_16x16x32_bf16(a1[i], b4[j], acc[4 + i][j], 0, 0, 0);
    }

    // ---- fast epilogue: hinge-support test only ----
    // C/D layout: col = lane&15, row = quad*4 + reg (verified)
    float hb[4];
#pragma unroll
    for (int j = 0; j < 4; ++j)
        hb[j] = 0.5f * sSqB[wc * 64 + j * 16 + rr] - 2.0f;

    float gm[4] = {-1e30f, -1e30f, -1e30f, -1e30f};
#pragma unroll
    for (int i = 0; i < 8; ++i) {
        const f32x4 sa4 = *(const f32x4*)&sSqA[wr * 128 + i * 16 + quad * 4];
#pragma unroll
        for (int rg = 0; rg < 4; ++rg) {
            const float ha = -0.5f * sa4[rg];
#pragma unroll
            for (int j = 0; j < 4; ++j)
                gm[j] = fmaxf(gm[j], acc[i][j][rg] + ha);
        }
    }

    float negS = 0.f;
    const bool wf = (gm[0] > hb[0]) | (gm[1] > hb[1]) | (gm[2] > hb[2]) | (gm[3] > hb[3]);
    if (__any(wf)) {   // rare: some pair has d < 4 (incl. self-pairs on diag blocks)
        float sb[4]; int lbv[4];
#pragma unroll
        for (int j = 0; j < 4; ++j) {
            int cl = wc * 64 + j * 16 + rr;
            sb[j]  = sSqB[cl];
            lbv[j] = sLabB[cl];
        }
#pragma unroll
        for (int i = 0; i < 8; ++i) {
            const f32x4 sa4 = *(const f32x4*)&sSqA[wr * 128 + i * 16 + quad * 4];
            const int4  la4 = *(const int4*)&sLabA[wr * 128 + i * 16 + quad * 4];
#pragma unroll
            for (int rg = 0; rg < 4; ++rg) {
                float sa = sa4[rg];
                int   la = ((const int*)&la4)[rg];
#pragma unroll
                for (int j = 0; j < 4; ++j) {
                    float d = fmaxf(sa + sb[j] - 2.0f * acc[i][j][rg], 0.0f);
                    float h = fmaxf(2.0f - sqrtf(d + 1e-9f), 0.f);
                    negS += (la == lbv[j]) ? 0.f : h * h;
                }
            }
        }
    }

    negS *= (bi == bj) ? 1.0f : 2.0f;

#pragma unroll
    for (int off = 32; off > 0; off >>= 1)
        negS += __shfl_down(negS, off);
    if (lane == 0) rN[wave] = negS;
    __syncthreads();
    if (tid == 0) {
        float tn = 0.f;
#pragma unroll
        for (int w = 0; w < 8; ++w) tn += rN[w];
        slots[k] = tn;
    }
}

// --- kernel 3: histogram + pos (analytic) + neg slot reduce + combine ---
__global__ __launch_bounds__(1024) void finalize_kernel(
    const float* __restrict__ slots, const int* __restrict__ lab,
    const float* __restrict__ sq, const float* __restrict__ posG,
    float* __restrict__ out)
{
    __shared__ int   hist[64];
    __shared__ float sP[16], sN[16];
    const int tid = threadIdx.x;
    if (tid < 64) hist[tid] = 0;
    __syncthreads();
    for (int i = tid; i < NPTS; i += 1024) atomicAdd(&hist[lab[i]], 1);
    __syncthreads();

    float p = 0.f, n = 0.f;
    for (int i = tid; i < NPTS; i += 1024) p += sq[i] * (float)hist[lab[i]];  // sum_c n_c S_c
    for (int i = tid; i < NTRI2; i += 1024) n += slots[i];
#pragma unroll
    for (int off = 32; off > 0; off >>= 1) {
        p += __shfl_down(p, off);
        n += __shfl_down(n, off);
    }
    const int wave = tid >> 6, lane = tid & 63;
    if (lane == 0) { sP[wave] = p; sN[wave] = n; }
    __syncthreads();
    if (tid == 0) {
        long long np = 0;
        for (int c = 0; c < 64; ++c) np += (long long)hist[c] * hist[c];
        float tp = 0.f, tn = 0.f;
#pragma unroll
        for (int w = 0; w < 16; ++w) { tp += sP[w]; tn += sN[w]; }
        double dnp = (double)np;
        double dnn = (double)NPTS * (double)NPTS - dnp;
        // dist_pos = 2*sum_c n_c S_c - 2*sum_c ||v_c||^2 ; pos = 0.5*dist_pos/np
        double pt = (dnp > 0.0) ? ((double)tp - (double)posG[0]) / dnp : 0.0;
        double nt = (dnn > 0.0) ? 0.5 * (double)tn / dnn : 0.0;
        out[0] = (float)(pt + nt);
    }
}

extern "C" void kernel_launch(void* const* d_in, const int* in_sizes, int n_in,
                              void* d_out, int out_size, void* d_ws, size_t ws_size,
                              hipStream_t stream) {
    const float* X   = (const float*)d_in[0];
    const int*   lab = (const int*)d_in[1];
    float*       out = (float*)d_out;

    char* ws = (char*)d_ws;
    unsigned short* Xbf     = (unsigned short*)(ws);                      // 2 MB
    float*          sq      = (float*)(ws + 2 * 1024 * 1024);             // 32 KB
    float*          slots   = (float*)(ws + 2 * 1024 * 1024 + 32 * 1024); // 2.1 KB
    float*          posG    = (float*)(ws + 2 * 1024 * 1024 + 64 * 1024); // 4 B
    float*          partial = (float*)(ws + 3 * 1024 * 1024);             // 6.6 MB

    prep_kernel<<<NPTS / 4, 256, 0, stream>>>(X, Xbf, sq, posG);
    classsum_kernel<<<CSBLK, 256, 0, stream>>>(Xbf, lab, partial);
    classred_kernel<<<25, 256, 0, stream>>>(partial, posG);
    pair_kernel<<<NTRI2, 512, 0, stream>>>(Xbf, lab, sq, slots);
    finalize_kernel<<<1, 1024, 0, stream>>>(slots, lab, sq, posG, out);
}